// Round 15
// baseline (611.291 us; speedup 1.0000x reference)
//
#include <hip/hip_runtime.h>
#include <cstdint>
#include <cstddef>

// ---------------------------------------------------------------------------
// CellGraphSAGE: 3x (SAGE-mean conv -> BN -> ReLU)
// dims: 128 -> 512 -> 256 -> 128, N=50000 nodes, E=800000 edges
// Round 26 = r25 champion (559.5us) + WIDE GEMM tiles (BN=256):
//  - Session invariant (r3-r25): GEMM time ~= staged bytes / 2-3.8 TB/s,
//    regardless of schedule/occupancy. staged(A) = nx * N*K*2B. Widening
//    the block tile 128x128 -> 128x256 (512 thr, 8 waves as 2 row x 4 col,
//    per-wave acc[4][4] unchanged) halves A-restaging:
//    L1 400->300 MB, L0 202->151, L2 102->77.
//  - 3-buf BK=32 (A 3x8KB + B 3x16KB = 72 KB LDS), vmcnt(6/3/0) ladder
//    (3 loads/thread/stage). launch_bounds(512,2).
//  - BNA fusion (k0 = kt*32 + quad*8), fused BN stats, m204 XCD swizzle
//    all carried over unchanged.
// ---------------------------------------------------------------------------

#define EPS_BN 1e-5f

typedef unsigned short ushort_t;
typedef __attribute__((ext_vector_type(8))) short short8;
typedef __attribute__((ext_vector_type(4))) float float4v;
typedef __attribute__((ext_vector_type(2))) float float2v;
typedef __attribute__((ext_vector_type(2))) unsigned int uint2v;
typedef __attribute__((ext_vector_type(4))) unsigned int uint4v;

__device__ __forceinline__ float bflo(unsigned int w) {
    union { unsigned int i; float f; } v; v.i = w << 16; return v.f;
}
__device__ __forceinline__ float bfhi(unsigned int w) {
    union { unsigned int i; float f; } v; v.i = w & 0xffff0000u; return v.f;
}
__device__ __forceinline__ ushort_t f2bf(float f) {
    union { float f; unsigned int i; } v; v.f = f;
    unsigned int r = v.i + 0x7fffu + ((v.i >> 16) & 1u);  // RNE
    return (ushort_t)(r >> 16);
}

// async 16B global -> LDS (wave-uniform base + lane*16)
__device__ __forceinline__ void async_copy16(void* lds, const void* g) {
    __builtin_amdgcn_global_load_lds(
        (const __attribute__((address_space(1))) unsigned int*)g,
        (__attribute__((address_space(3))) unsigned int*)lds, 16, 0, 0);
}

__device__ __forceinline__ void edge_sd(const int* __restrict__ p, int e, int ne,
                                        bool is64, int& s, int& d) {
    if (is64) { s = p[2 * e];  d = p[2 * ne + 2 * e]; }
    else      { s = p[e];      d = p[ne + e]; }
}
__device__ __forceinline__ int edge_d(const int* __restrict__ p, int e, int ne, bool is64) {
    return is64 ? p[2 * ne + 2 * e] : p[ne + e];
}

// in-block edge-format probe: int64 storage (values < 2^31) => odd int32
// words are all 0; random int32 ids make 64 consecutive zeros impossible.
__device__ __forceinline__ bool detect_is64(const int* __restrict__ edges,
                                            int* sh_flag, int t) {
    if (t == 0) *sh_flag = 1;
    __syncthreads();
    if (t < 64 && edges[2 * t + 1] != 0) *sh_flag = 0;  // same-value race ok
    __syncthreads();
    return *sh_flag != 0;
}

// ---------------- bucket-sort CSR build ------------------------------------
#define EPB 2048

__global__ __launch_bounds__(256) void bhist_kernel(
    const int* __restrict__ edges, int ne, int* __restrict__ gcnt) {
    __shared__ int h[256];
    __shared__ int f64;
    int t = threadIdx.x;
    bool is64 = detect_is64(edges, &f64, t);
    h[t] = 0;
    __syncthreads();
    int base_e = blockIdx.x * EPB;
    #pragma unroll
    for (int u = 0; u < EPB / 256; ++u) {
        int i = base_e + u * 256 + t;
        if (i < ne) atomicAdd(&h[edge_d(edges, i, ne, is64) >> 8], 1);
    }
    __syncthreads();
    if (h[t]) atomicAdd(&gcnt[t], h[t]);
}

__global__ __launch_bounds__(256) void bscan_kernel(
    const int* __restrict__ gcnt, int nb, int ne,
    int* __restrict__ bbase, int* __restrict__ bcur) {
    __shared__ int sh[256];
    int t = threadIdx.x;
    int v = (t < nb) ? gcnt[t] : 0;
    sh[t] = v;
    __syncthreads();
    for (int o = 1; o < 256; o <<= 1) {
        int x = (t >= o) ? sh[t - o] : 0;
        __syncthreads();
        sh[t] += x;
        __syncthreads();
    }
    int excl = sh[t] - v;
    if (t < nb) { bbase[t] = excl; bcur[t] = excl; }
    if (t == nb) bbase[t] = ne;
    if (t == 0 && nb == 256) bbase[256] = ne;
}

__global__ __launch_bounds__(256) void bscatter_kernel(
    const int* __restrict__ edges, int ne,
    int* __restrict__ bcur, int* __restrict__ packed) {
    __shared__ int h[256];
    __shared__ int chunkb[256];
    __shared__ int lcur[256];
    __shared__ int f64;
    int t = threadIdx.x;
    bool is64 = detect_is64(edges, &f64, t);
    h[t] = 0;
    lcur[t] = 0;
    __syncthreads();
    int base_e = blockIdx.x * EPB;
    int ent[EPB / 256], eb[EPB / 256];
    #pragma unroll
    for (int u = 0; u < EPB / 256; ++u) {
        int i = base_e + u * 256 + t;
        if (i < ne) {
            int s, d;
            edge_sd(edges, i, ne, is64, s, d);
            ent[u] = s | ((d & 255) << 24);
            eb[u] = d >> 8;
            atomicAdd(&h[eb[u]], 1);
        } else eb[u] = -1;
    }
    __syncthreads();
    if (h[t]) chunkb[t] = atomicAdd(&bcur[t], h[t]);
    __syncthreads();
    #pragma unroll
    for (int u = 0; u < EPB / 256; ++u) {
        if (eb[u] >= 0) {
            int lp = atomicAdd(&lcur[eb[u]], 1);
            packed[chunkb[eb[u]] + lp] = ent[u];
        }
    }
}

__global__ __launch_bounds__(256) void bbuild_kernel(
    const int* __restrict__ packed, const int* __restrict__ bbase,
    int* __restrict__ rowptr, int* __restrict__ csr_src, int n) {
    __shared__ int h[256];
    __shared__ int cur[256];
    int t = threadIdx.x;
    int bb = blockIdx.x;
    int base = bbase[bb], cnt = bbase[bb + 1] - base;
    h[t] = 0;
    __syncthreads();
    for (int i = t; i < cnt; i += 256)
        atomicAdd(&h[(unsigned)packed[base + i] >> 24], 1);
    __syncthreads();
    int v = h[t];
    for (int o = 1; o < 256; o <<= 1) {
        int x = (t >= o) ? h[t - o] : 0;
        __syncthreads();
        h[t] += x;
        __syncthreads();
    }
    int excl = h[t] - v;
    int node = bb * 256 + t;
    if (node <= n) rowptr[node] = base + excl;
    cur[t] = excl;
    __syncthreads();
    for (int i = t; i < cnt; i += 256) {
        int e = packed[base + i];
        int lp = atomicAdd(&cur[(unsigned)e >> 24], 1);
        csr_src[base + lp] = e & 0xffffff;
    }
}

// ---------------- merged prep: x->bf16 + 3 transposed weight preps ---------
__global__ void prep_all_kernel(
    const float* __restrict__ x, ushort_t* __restrict__ xb, int nxb,
    const float* __restrict__ Wl0, const float* __restrict__ Wr0,
    ushort_t* __restrict__ WT0, int nb0,
    const float* __restrict__ Wl1, const float* __restrict__ Wr1,
    ushort_t* __restrict__ WT1c, int nb1,
    const float* __restrict__ Wl2, const float* __restrict__ Wr2,
    ushort_t* __restrict__ WT2c) {
    const int D0 = 128, D1 = 512, D2 = 256, D3 = 128;
    int b = blockIdx.x;
    if (b < nxb) {
        int i = b * 256 + threadIdx.x;
        xb[i] = f2bf(x[i]);
        return;
    }
    b -= nxb;
    if (b < nb0) {
        int idx = b * 256 + threadIdx.x;
        int K2 = 2 * D0;
        int nn = idx / K2, k = idx - nn * K2;
        float v = (k < D0) ? Wl0[(size_t)k * D1 + nn] : Wr0[(size_t)(k - D0) * D1 + nn];
        WT0[idx] = f2bf(v);
        return;
    }
    b -= nb0;
    if (b < nb1) {
        int idx = b * 256 + threadIdx.x;
        int nn = idx / D1, k = idx - nn * D1;
        float v = (nn < D2) ? Wl1[(size_t)k * D2 + nn] : Wr1[(size_t)k * D2 + (nn - D2)];
        WT1c[idx] = f2bf(v);
        return;
    }
    b -= nb1;
    {
        int idx = b * 256 + threadIdx.x;
        int nn = idx / D2, k = idx - nn * D2;
        float v = (nn < D3) ? Wl2[(size_t)k * D3 + nn] : Wr2[(size_t)k * D3 + (nn - D3)];
        WT2c[idx] = f2bf(v);
    }
}

// ---------------- aggregation helpers --------------------------------------
template <int VEC> struct VecT;
template <> struct VecT<2> { using T = unsigned int; };
template <> struct VecT<4> { using T = uint2v; };
template <> struct VecT<8> { using T = uint4v; };

template <int VEC>
__device__ __forceinline__ void vunpack(typename VecT<VEC>::T v, unsigned int* w) {
    if constexpr (VEC == 2) { w[0] = v; }
    else if constexpr (VEC == 4) { w[0] = v.x; w[1] = v.y; }
    else { w[0] = v.x; w[1] = v.y; w[2] = v.z; w[3] = v.w; }
}

template <int VEC>
__device__ __forceinline__ void vaccum(typename VecT<VEC>::T v, float* acc) {
    unsigned int w[VEC / 2];
    vunpack<VEC>(v, w);
    #pragma unroll
    for (int i = 0; i < VEC / 2; ++i) {
        acc[2 * i + 0] += bflo(w[i]);
        acc[2 * i + 1] += bfhi(w[i]);
    }
}

// gather loop, x16 main unroll with cascade tail (order-preserving)
template <int VEC>
__device__ __forceinline__ void gather_sum(
    const ushort_t* __restrict__ base, const int* __restrict__ csr_src,
    int e0, int e1, int rstride, float* acc) {
    using VT = typename VecT<VEC>::T;
    int e = e0;
    for (; e + 16 <= e1; e += 16) {
        VT v[16];
        #pragma unroll
        for (int u = 0; u < 16; ++u)
            v[u] = *(const VT*)(base + (size_t)csr_src[e + u] * rstride);
        #pragma unroll
        for (int u = 0; u < 16; ++u) vaccum<VEC>(v[u], acc);
    }
    if (e + 8 <= e1) {
        VT v[8];
        #pragma unroll
        for (int u = 0; u < 8; ++u)
            v[u] = *(const VT*)(base + (size_t)csr_src[e + u] * rstride);
        #pragma unroll
        for (int u = 0; u < 8; ++u) vaccum<VEC>(v[u], acc);
        e += 8;
    }
    if (e + 4 <= e1) {
        VT v[4];
        #pragma unroll
        for (int u = 0; u < 4; ++u)
            v[u] = *(const VT*)(base + (size_t)csr_src[e + u] * rstride);
        #pragma unroll
        for (int u = 0; u < 4; ++u) vaccum<VEC>(v[u], acc);
        e += 4;
    }
    if (e + 2 <= e1) {
        VT v0 = *(const VT*)(base + (size_t)csr_src[e] * rstride);
        VT v1 = *(const VT*)(base + (size_t)csr_src[e + 1] * rstride);
        vaccum<VEC>(v0, acc); vaccum<VEC>(v1, acc);
        e += 2;
    }
    if (e < e1)
        vaccum<VEC>(*(const VT*)(base + (size_t)csr_src[e] * rstride), acc);
}

// ---------------- plain aggregation (layer 0): bf16 mean -------------------
// grid-stride at exactly-resident block count
template <int VEC>
__global__ __launch_bounds__(256) void aggregate_wave_kernel(
    const ushort_t* __restrict__ h, ushort_t* __restrict__ mean,
    const int* __restrict__ rowptr, const int* __restrict__ csr_src, int nnodes) {
    const int din = VEC * 64;
    const int wave = threadIdx.x >> 6;
    const int lane = threadIdx.x & 63;
    const int wstride = gridDim.x * 4;
    using VT = typename VecT<VEC>::T;
    for (int wid = blockIdx.x * 4 + wave; wid < nnodes; wid += wstride) {
        int e0 = rowptr[wid], e1 = rowptr[wid + 1];
        float acc[VEC];
        #pragma unroll
        for (int i = 0; i < VEC; ++i) acc[i] = 0.f;
        gather_sum<VEC>(h + (size_t)lane * VEC, csr_src, e0, e1, din, acc);

        int deg = e1 - e0;
        float scale = 1.0f / (float)(deg > 1 ? deg : 1);
        unsigned int o[VEC / 2];
        #pragma unroll
        for (int i = 0; i < VEC / 2; ++i)
            o[i] = (unsigned int)f2bf(acc[2 * i] * scale) |
                   ((unsigned int)f2bf(acc[2 * i + 1] * scale) << 16);
        VT ov;
        if constexpr (VEC == 2) { ov = o[0]; }
        else if constexpr (VEC == 4) { ov.x = o[0]; ov.y = o[1]; }
        else { ov.x = o[0]; ov.y = o[1]; ov.z = o[2]; ov.w = o[3]; }
        *(VT*)(mean + (size_t)wid * din + (size_t)lane * VEC) = ov;
    }
}

// ---------------- fused aggregate + add + BN-stats, bf16 out (L1/L2) -------
// Each col is owned by exactly one lane -> per-lane f32 sum/sumsq registers
// across the grid-stride loop; LDS-reduce across the 4 waves; 2*D atomics
// per block at the end (same order as the deleted colstats kernel).
template <int VEC>  // VEC = D/64
__global__ __launch_bounds__(256) void aggregate_add_kernel(
    const ushort_t* __restrict__ PR, const float* __restrict__ bias,
    ushort_t* __restrict__ pre,
    const int* __restrict__ rowptr, const int* __restrict__ csr_src, int nnodes,
    float* __restrict__ gsum, float* __restrict__ gsq) {
    const int D = VEC * 64;
    const int stride = 2 * D;
    __shared__ float s_red[2][4][VEC * 64];
    const int wave = threadIdx.x >> 6;
    const int lane = threadIdx.x & 63;
    const int wstride = gridDim.x * 4;
    using VT = typename VecT<VEC>::T;

    float ssum[VEC], ssq[VEC];
    #pragma unroll
    for (int i = 0; i < VEC; ++i) { ssum[i] = 0.f; ssq[i] = 0.f; }

    for (int wid = blockIdx.x * 4 + wave; wid < nnodes; wid += wstride) {
        int e0 = rowptr[wid], e1 = rowptr[wid + 1];
        float acc[VEC];
        #pragma unroll
        for (int i = 0; i < VEC; ++i) acc[i] = 0.f;
        gather_sum<VEC>(PR + (size_t)lane * VEC, csr_src, e0, e1, stride, acc);

        int deg = e1 - e0;
        float scale = 1.0f / (float)(deg > 1 ? deg : 1);

        VT rv = *(const VT*)(PR + (size_t)wid * stride + D + (size_t)lane * VEC);
        unsigned int rw[VEC / 2];
        vunpack<VEC>(rv, rw);
        float o[VEC];
        #pragma unroll
        for (int i = 0; i < VEC / 2; ++i) {
            o[2 * i + 0] = bflo(rw[i]);
            o[2 * i + 1] = bfhi(rw[i]);
        }
        #pragma unroll
        for (int i = 0; i < VEC; ++i) {
            o[i] += acc[i] * scale + bias[lane * VEC + i];
            ssum[i] += o[i];
            ssq[i] += o[i] * o[i];
        }

        unsigned int ow[VEC / 2];
        #pragma unroll
        for (int i = 0; i < VEC / 2; ++i)
            ow[i] = (unsigned int)f2bf(o[2 * i]) | ((unsigned int)f2bf(o[2 * i + 1]) << 16);
        VT ov;
        if constexpr (VEC == 2) { ov = ow[0]; }
        else if constexpr (VEC == 4) { ov.x = ow[0]; ov.y = ow[1]; }
        else { ov.x = ow[0]; ov.y = ow[1]; ov.z = ow[2]; ov.w = ow[3]; }
        *(VT*)(pre + (size_t)wid * D + (size_t)lane * VEC) = ov;
    }

    // block-level stats reduce (all threads reach here; no barrier in loop)
    #pragma unroll
    for (int i = 0; i < VEC; ++i) {
        s_red[0][wave][lane * VEC + i] = ssum[i];
        s_red[1][wave][lane * VEC + i] = ssq[i];
    }
    __syncthreads();
    int t = threadIdx.x;
    if (t < D) {
        float a = s_red[0][0][t] + s_red[0][1][t] + s_red[0][2][t] + s_red[0][3][t];
        float q = s_red[1][0][t] + s_red[1][1][t] + s_red[1][2][t] + s_red[1][3][t];
        atomicAdd(&gsum[t], a);
        atomicAdd(&gsq[t], q);
    }
}

// ---------------- MFMA GEMM, 128x256 tile, 512 thr, BK=32, 3-buf -----------
// 8 waves as 2 row-waves x 4 col-waves; per-wave 64x64 tile (acc[4][4]).
// Wide BN=256 halves A-restaging (staged-bytes invariant, r3-r25).
// Triple-buffered BK=32: stages kt+2 while computing kt; vmcnt(6)/(3)/(0)
// ladder (3 loads/thread/stage). LDS 72 KB (A 3x8 + B 3x16) -> 2 blocks/CU.
// m204 bijective XCD-chunk swizzle. setprio around MFMA.
// DUAL: C = [A1|A2] @ BT^T ; BIAS adds bias[col]; STATS: fused BN col-stats.
// BNA: per-channel scale/shift+ReLU+bf16-round on A fragments after LDS
// read; fragment at LDS pos (quad^sw3) holds GLOBAL k-chunk quad (the
// staging swizzle is an involution) -> channel base k0 = kt*32 + quad*8.
template <bool DUAL, bool BIAS, bool STATS, bool BNA>
__global__ __launch_bounds__(512, 2) void gemm_glds_kernel(
    const ushort_t* __restrict__ A1, const ushort_t* __restrict__ A2,
    const ushort_t* __restrict__ BT, const float* __restrict__ bias,
    ushort_t* __restrict__ Cb, int N, int K1, int Ktot, int Wtot, int nxShift,
    float* __restrict__ gsum, float* __restrict__ gsq,
    const float* __restrict__ bsum, const float* __restrict__ bsq,
    const float* __restrict__ bng, const float* __restrict__ bnb) {
    __shared__ ushort_t As[3 * 128 * 32];  // 3 x 8 KB
    __shared__ ushort_t Bs[3 * 256 * 32];  // 3 x 16 KB
    __shared__ float bnsc[BNA ? 512 : 1];
    __shared__ float bnsh[BNA ? 512 : 1];

    const int tid = threadIdx.x;
    const int wave = tid >> 6;
    const int lane = tid & 63;
    const int quad = lane >> 4;
    const int l15 = lane & 15;
    const int sw3 = l15 & 3;

    // bijective XCD-chunk swizzle (m204): dispatch order o -> logical wgid
    const int nwg = gridDim.x;
    const int q = nwg >> 3, rr = nwg & 7;
    const int o = blockIdx.x;
    const int xcd = o & 7, sub = o >> 3;
    const int wgid = (xcd < rr ? xcd * (q + 1) : rr * (q + 1) + (xcd - rr) * q) + sub;
    const int bx = wgid & ((1 << nxShift) - 1);
    const int by = wgid >> nxShift;

    const int rowBase = by * 128;
    const int colBase = bx * 256;
    const int wm = (wave >> 2) * 64;   // 0/64      (2 row-waves)
    const int wn = (wave & 3) * 64;    // 0..192    (4 col-waves)

    if constexpr (BNA) {
        // build per-channel scale/shift table: v' = v*sc + sh, then ReLU
        for (int t = tid; t < K1; t += 512) {
            float m = bsum[t] / (float)N;
            float inv = rsqrtf(bsq[t] / (float)N - m * m + EPS_BN);
            float sc = bng[t] * inv;
            bnsc[t] = sc;
            bnsh[t] = bnb[t] - m * sc;
        }
        __syncthreads();
    }

    float4v acc[4][4];
    #pragma unroll
    for (int i = 0; i < 4; ++i)
        #pragma unroll
        for (int j = 0; j < 4; ++j)
            acc[i][j] = (float4v){0.f, 0.f, 0.f, 0.f};

    const int nkt = Ktot / 32;
    const int khalf = K1 / 32;

    // stage one BK=32 tile: A 512 x 16B chunks (1/thread), B 1024 (2/thread)
    auto stage = [&](int buf, int kt) {
        const ushort_t* Asrc = A1;
        int kg = kt * 32;
        if (DUAL && kt >= khalf) { Asrc = A2; kg = (kt - khalf) * 32; }
        const int kb = kt * 32;
        {
            int c = tid;                       // 0..511 = 128 rows x 4 chunks
            int r = c >> 2, cc = c & 3;
            int off = (cc ^ (r & 3)) * 8;
            int grow = rowBase + r;
            if (grow >= N) grow = N - 1;
            async_copy16(&As[buf * 4096 + c * 8], Asrc + (size_t)grow * K1 + kg + off);
        }
        #pragma unroll
        for (int u = 0; u < 2; ++u) {
            int c = u * 512 + tid;             // 0..1023 = 256 cols x 4 chunks
            int r = c >> 2, cc = c & 3;
            int off = (cc ^ (r & 3)) * 8;
            async_copy16(&Bs[buf * 8192 + c * 8], BT + (size_t)(colBase + r) * Ktot + kb + off);
        }
    };

    stage(0, 0);
    if (nkt > 1) stage(1, 1);
    int cur = 0;
    for (int kt = 0; kt < nkt; ++kt) {
        if (kt + 2 < nkt) {
            int nb = cur + 2; if (nb >= 3) nb -= 3;
            stage(nb, kt + 2);
            // kt's 3 loads retired; kt+1's 3 + kt+2's 3 stay in flight
            asm volatile("s_waitcnt vmcnt(6)\n\ts_barrier" ::: "memory");
        } else if (kt + 1 < nkt) {
            asm volatile("s_waitcnt vmcnt(3)\n\ts_barrier" ::: "memory");
        } else {
            asm volatile("s_waitcnt vmcnt(0)\n\ts_barrier" ::: "memory");
        }

        short8 af[4], bf4[4];
        #pragma unroll
        for (int i = 0; i < 4; ++i)
            af[i] = *(const short8*)&As[cur * 4096 + (wm + i * 16 + l15) * 32 + (quad ^ sw3) * 8];
        #pragma unroll
        for (int j = 0; j < 4; ++j)
            bf4[j] = *(const short8*)&Bs[cur * 8192 + (wn + j * 16 + l15) * 32 + (quad ^ sw3) * 8];

        if constexpr (BNA) {
            // fragment holds GLOBAL k = kt*32 + quad*8 + [0,8)  (de-swizzled)
            int k0 = kt * 32 + quad * 8;
            #pragma unroll
            for (int e = 0; e < 8; ++e) {
                float sc = bnsc[k0 + e];
                float sh = bnsh[k0 + e];
                #pragma unroll
                for (int i = 0; i < 4; ++i) {
                    unsigned int u = ((unsigned int)(unsigned short)af[i][e]) << 16;
                    union { unsigned int w; float f; } cv; cv.w = u;
                    float v = cv.f * sc + sh;
                    v = v > 0.f ? v : 0.f;
                    af[i][e] = (short)f2bf(v);
                }
            }
        }

        __builtin_amdgcn_s_setprio(1);
        #pragma unroll
        for (int i = 0; i < 4; ++i)
            #pragma unroll
            for (int j = 0; j < 4; ++j)
                acc[i][j] = __builtin_amdgcn_mfma_f32_16x16x32_bf16(bf4[j], af[i], acc[i][j], 0, 0, 0);
        __builtin_amdgcn_s_setprio(0);
        // all waves done reading buf cur before a later stage() overwrites it
        asm volatile("s_barrier" ::: "memory");
        cur = (cur == 2) ? 0 : cur + 1;
    }

    float cs[4][4], cq[4][4];
    if constexpr (STATS) {
        #pragma unroll
        for (int j = 0; j < 4; ++j)
            #pragma unroll
            for (int r = 0; r < 4; ++r) { cs[j][r] = 0.f; cq[j][r] = 0.f; }
    }

    // epilogue: per-wave 4KB LDS restage -> full-line bf16 stores
    // 8 waves x 2048 shorts = 16K shorts <= Bs (24K shorts)
    ushort_t* lws = &Bs[wave * 2048];
    #pragma unroll
    for (int p = 0; p < 2; ++p) {
        #pragma unroll
        for (int jj = 0; jj < 2; ++jj) {
            int j = 2 * p + jj;
            float4 bv = make_float4(0.f, 0.f, 0.f, 0.f);
            if (BIAS) bv = *(const float4*)(bias + colBase + wn + j * 16 + quad * 4);
            #pragma unroll
            for (int i = 0; i < 4; ++i) {
                float v0 = acc[i][j][0] + bv.x;
                float v1 = acc[i][j][1] + bv.y;
                float v2 = acc[i][j][2] + bv.z;
                float v3 = acc[i][j][3] + bv.w;
                if constexpr (STATS) {
                    if (rowBase + wm + i * 16 + l15 < N) {
                        cs[j][0] += v0; cq[j][0] += v0 * v0;
                        cs[j][1] += v1; cq[j][1] += v1 * v1;
                        cs[j][2] += v2; cq[j][2] += v2 * v2;
                        cs[j][3] += v3; cq[j][3] += v3 * v3;
                    }
                }
                uint2 pk;
                pk.x = (unsigned int)f2bf(v0) | ((unsigned int)f2bf(v1) << 16);
                pk.y = (unsigned int)f2bf(v2) | ((unsigned int)f2bf(v3) << 16);
                *(uint2*)&lws[(i * 16 + l15) * 32 + jj * 16 + quad * 4] = pk;
            }
        }
        __syncthreads();
        #pragma unroll
        for (int it = 0; it < 4; ++it) {
            int c = it * 64 + lane;
            int row = c >> 2, coff = (c & 3) * 8;
            int grow = rowBase + wm + row;
            if (grow < N) {
                uint4 v = *(const uint4*)&lws[row * 32 + coff];
                *(uint4*)(Cb + (size_t)grow * Wtot + colBase + wn + p * 32 + coff) = v;
            }
        }
        __syncthreads();
    }

    if constexpr (STATS) {
        // reduce over l15 (16 lanes share same col, different rows)
        #pragma unroll
        for (int j = 0; j < 4; ++j)
            #pragma unroll
            for (int r = 0; r < 4; ++r) {
                #pragma unroll
                for (int m = 1; m < 16; m <<= 1) {
                    cs[j][r] += __shfl_xor(cs[j][r], m);
                    cq[j][r] += __shfl_xor(cq[j][r], m);
                }
            }
        if (l15 == 0) {
            #pragma unroll
            for (int j = 0; j < 4; ++j)
                #pragma unroll
                for (int r = 0; r < 4; ++r) {
                    int col = colBase + wn + j * 16 + quad * 4 + r;
                    atomicAdd(&gsum[col], cs[j][r]);
                    atomicAdd(&gsq[col], cq[j][r]);
                }
        }
    }
}

// ---------------- BN apply (bf16 in, f32 out: final layer) -----------------
__global__ void bn_relu_b2f_kernel(const ushort_t* __restrict__ h, float* __restrict__ hf,
                                   int N, int D,
                                   const float* __restrict__ sum, const float* __restrict__ sumsq,
                                   const float* __restrict__ g, const float* __restrict__ b) {
    size_t idx = (size_t)blockIdx.x * blockDim.x + threadIdx.x;
    size_t tot = (size_t)N * D / 2;
    if (idx >= tot) return;
    int cp = (int)(idx & (size_t)(D / 2 - 1));
    int c0 = cp * 2, c1 = c0 + 1;
    float m0 = sum[c0] / (float)N, m1 = sum[c1] / (float)N;
    float i0 = rsqrtf(sumsq[c0] / (float)N - m0 * m0 + EPS_BN);
    float i1 = rsqrtf(sumsq[c1] / (float)N - m1 * m1 + EPS_BN);
    unsigned int w = ((const unsigned int*)h)[idx];
    float v0 = g[c0] * (bflo(w) - m0) * i0 + b[c0];
    float v1 = g[c1] * (bfhi(w) - m1) * i1 + b[c1];
    float2v o;
    o.x = v0 > 0.f ? v0 : 0.f;
    o.y = v1 > 0.f ? v1 : 0.f;
    *(float2v*)(hf + idx * 2) = o;
}

// ---------------------------------------------------------------------------
extern "C" void kernel_launch(void* const* d_in, const int* in_sizes, int n_in,
                              void* d_out, int out_size, void* d_ws, size_t ws_size,
                              hipStream_t stream) {
    const float* x     = (const float*)d_in[0];
    const int*   edges = (const int*)d_in[1];
    const float* Wl0 = (const float*)d_in[2];
    const float* bl0 = (const float*)d_in[3];
    const float* Wr0 = (const float*)d_in[4];
    const float* g0  = (const float*)d_in[5];
    const float* b0  = (const float*)d_in[6];
    const float* Wl1 = (const float*)d_in[7];
    const float* bl1 = (const float*)d_in[8];
    const float* Wr1 = (const float*)d_in[9];
    const float* g1  = (const float*)d_in[10];
    const float* b1  = (const float*)d_in[11];
    const float* Wl2 = (const float*)d_in[12];
    const float* bl2 = (const float*)d_in[13];
    const float* Wr2 = (const float*)d_in[14];
    const float* g2  = (const float*)d_in[15];
    const float* b2  = (const float*)d_in[16];

    const int D0 = 128, D1 = 512, D2 = 256, D3 = 128;
    const int n  = in_sizes[0] / D0;   // 50000
    const int ne = in_sizes[1] / 2;    // 800000
    const int NB = (n + 255) >> 8;     // 196 buckets

    // ---- workspace layout (zeroed block first -> one memset) ----
    char* base = (char*)d_ws;
    size_t off = 0;
    auto alloc = [&](size_t bytes) -> char* {
        char* p = base + off;
        off = (off + bytes + 255) & ~(size_t)255;
        return p;
    };
    int*      gcnt    = (int*)alloc(256 * 4);
    float*    stats   = (float*)alloc(6 * 512 * 4);
    size_t    zero_span = off;
    int*      bbase   = (int*)alloc(257 * 4);
    int*      bcur    = (int*)alloc(256 * 4);
    int*      packed  = (int*)alloc((size_t)ne * 4);
    int*      rowptr  = (int*)alloc((size_t)(n + 1) * 4);
    int*      csr_src = (int*)alloc((size_t)ne * 4);
    ushort_t* xb      = (ushort_t*)alloc((size_t)n * D0 * 2);
    ushort_t* mb      = (ushort_t*)alloc((size_t)n * 512 * 2);   // mean(L0) / PR(L1,L2)
    ushort_t* hpre    = (ushort_t*)alloc((size_t)n * 512 * 2);   // bf16 pre-BN
    ushort_t* WT0     = (ushort_t*)alloc((size_t)D1 * 2 * D0 * 2);
    ushort_t* WT1c    = (ushort_t*)alloc((size_t)(2 * D2) * D1 * 2);
    ushort_t* WT2c    = (ushort_t*)alloc((size_t)(2 * D3) * D2 * 2);
    float*    out     = (float*)d_out;
    (void)ws_size; (void)n_in; (void)out_size;

    hipMemsetAsync(base, 0, zero_span, stream);

    // ---- bucket-sort CSR build (edge format detected in-block) ----
    int ablk = (ne + EPB - 1) / EPB;
    bhist_kernel<<<ablk, 256, 0, stream>>>(edges, ne, gcnt);
    bscan_kernel<<<1, 256, 0, stream>>>(gcnt, NB, ne, bbase, bcur);
    bscatter_kernel<<<ablk, 256, 0, stream>>>(edges, ne, bcur, packed);
    bbuild_kernel<<<NB, 256, 0, stream>>>(packed, bbase, rowptr, csr_src, n);

    // ---- merged prep (x->bf16 + all weight transposes) ----
    const int nxb = (n * D0) / 256;               // 25000
    const int nb0 = (D1 * 2 * D0) / 256;          // 512
    const int nb1 = (2 * D2 * D1) / 256;          // 1024
    const int nb2 = (2 * D3 * D2) / 256;          // 256
    prep_all_kernel<<<nxb + nb0 + nb1 + nb2, 256, 0, stream>>>(
        x, xb, nxb, Wl0, Wr0, WT0, nb0, Wl1, Wr1, WT1c, nb1, Wl2, Wr2, WT2c);

    const int aggGrid = 2048;                // exactly-resident: 8 blocks/CU
    const int rowBlocks = (n + 127) / 128;   // 128-row GEMM tiles (391)
    float* st0 = stats + 0 * 1024;
    float* st1 = stats + 1 * 1024;
    float* st2 = stats + 2 * 1024;

    // ---- layer 0: 128 -> 512 (aggregate-first: din < dout) ----
    aggregate_wave_kernel<2><<<aggGrid, 256, 0, stream>>>(xb, mb, rowptr, csr_src, n);
    // 256-wide tiles: nx = 512/256 = 2 -> nxShift=1, grid 2*391
    gemm_glds_kernel<true, true, true, false><<<2 * rowBlocks, 512, 0, stream>>>(
        mb, xb, WT0, bl0, hpre, n, D0, 2 * D0, D1, 1, st0, st0 + 512,
        nullptr, nullptr, nullptr, nullptr);
    // (BN-apply for L0 fused into L1 GEMM's A path)

    // ---- layer 1: 512 -> 256 (project-first, fused [P|R], BN-A fused) ----
    gemm_glds_kernel<false, false, false, true><<<2 * rowBlocks, 512, 0, stream>>>(
        hpre, nullptr, WT1c, nullptr, mb, n, D1, D1, 2 * D2, 1, nullptr, nullptr,
        st0, st0 + 512, g0, b0);                                  // PR1 = bn(hpre) @ [Wl1|Wr1]
    aggregate_add_kernel<4><<<aggGrid, 256, 0, stream>>>(
        mb, bl1, hpre, rowptr, csr_src, n, st1, st1 + 512);       // pre = mean(P)+R+bl1 (+stats)

    // ---- layer 2: 256 -> 128 (project-first, fused [P|R], BN-A fused) ----
    // out width 256 = one panel -> nxShift=0, grid 391
    gemm_glds_kernel<false, false, false, true><<<rowBlocks, 512, 0, stream>>>(
        hpre, nullptr, WT2c, nullptr, mb, n, D2, D2, 2 * D3, 0, nullptr, nullptr,
        st1, st1 + 512, g1, b1);                                  // PR2 = bn(hpre) @ [Wl2|Wr2]
    aggregate_add_kernel<2><<<aggGrid, 256, 0, stream>>>(
        mb, bl2, hpre, rowptr, csr_src, n, st2, st2 + 512);       // pre = mean(P)+R+bl2 (+stats)
    bn_relu_b2f_kernel<<<((size_t)n * D3 / 2 + 255) / 256, 256, 0, stream>>>(
        hpre, out, n, D3, st2, st2 + 512, g2, b2);
}

// Round 17
// 553.242 us; speedup vs baseline: 1.1049x; 1.1049x over previous
//
#include <hip/hip_runtime.h>
#include <cstdint>
#include <cstddef>

// ---------------------------------------------------------------------------
// CellGraphSAGE: 3x (SAGE-mean conv -> BN -> ReLU)
// dims: 128 -> 512 -> 256 -> 128, N=50000 nodes, E=800000 edges
// Round 28 == champion (559.5 us measured, round 14; resubmit after infra
// failure in round 16).
//  - GEMM: 128x128 tile, 256 thr, BK=32 triple-buffered, vmcnt(8/4/0)
//    ladder, launch_bounds(256,4), m204 XCD swizzle, setprio.
//  - BNA fusion: BN-apply+ReLU on consumer GEMM A fragments (k0=kt*32+quad*8).
//  - BN col-stats fused into producers (GEMM L0 epilogue, agg L1/L2).
//  Session-final configuration.
// ---------------------------------------------------------------------------

#define EPS_BN 1e-5f

typedef unsigned short ushort_t;
typedef __attribute__((ext_vector_type(8))) short short8;
typedef __attribute__((ext_vector_type(4))) float float4v;
typedef __attribute__((ext_vector_type(2))) float float2v;
typedef __attribute__((ext_vector_type(2))) unsigned int uint2v;
typedef __attribute__((ext_vector_type(4))) unsigned int uint4v;

__device__ __forceinline__ float bflo(unsigned int w) {
    union { unsigned int i; float f; } v; v.i = w << 16; return v.f;
}
__device__ __forceinline__ float bfhi(unsigned int w) {
    union { unsigned int i; float f; } v; v.i = w & 0xffff0000u; return v.f;
}
__device__ __forceinline__ ushort_t f2bf(float f) {
    union { float f; unsigned int i; } v; v.f = f;
    unsigned int r = v.i + 0x7fffu + ((v.i >> 16) & 1u);  // RNE
    return (ushort_t)(r >> 16);
}

// async 16B global -> LDS (wave-uniform base + lane*16)
__device__ __forceinline__ void async_copy16(void* lds, const void* g) {
    __builtin_amdgcn_global_load_lds(
        (const __attribute__((address_space(1))) unsigned int*)g,
        (__attribute__((address_space(3))) unsigned int*)lds, 16, 0, 0);
}

__device__ __forceinline__ void edge_sd(const int* __restrict__ p, int e, int ne,
                                        bool is64, int& s, int& d) {
    if (is64) { s = p[2 * e];  d = p[2 * ne + 2 * e]; }
    else      { s = p[e];      d = p[ne + e]; }
}
__device__ __forceinline__ int edge_d(const int* __restrict__ p, int e, int ne, bool is64) {
    return is64 ? p[2 * ne + 2 * e] : p[ne + e];
}

// in-block edge-format probe: int64 storage (values < 2^31) => odd int32
// words are all 0; random int32 ids make 64 consecutive zeros impossible.
__device__ __forceinline__ bool detect_is64(const int* __restrict__ edges,
                                            int* sh_flag, int t) {
    if (t == 0) *sh_flag = 1;
    __syncthreads();
    if (t < 64 && edges[2 * t + 1] != 0) *sh_flag = 0;  // same-value race ok
    __syncthreads();
    return *sh_flag != 0;
}

// ---------------- bucket-sort CSR build ------------------------------------
#define EPB 2048

__global__ __launch_bounds__(256) void bhist_kernel(
    const int* __restrict__ edges, int ne, int* __restrict__ gcnt) {
    __shared__ int h[256];
    __shared__ int f64;
    int t = threadIdx.x;
    bool is64 = detect_is64(edges, &f64, t);
    h[t] = 0;
    __syncthreads();
    int base_e = blockIdx.x * EPB;
    #pragma unroll
    for (int u = 0; u < EPB / 256; ++u) {
        int i = base_e + u * 256 + t;
        if (i < ne) atomicAdd(&h[edge_d(edges, i, ne, is64) >> 8], 1);
    }
    __syncthreads();
    if (h[t]) atomicAdd(&gcnt[t], h[t]);
}

__global__ __launch_bounds__(256) void bscan_kernel(
    const int* __restrict__ gcnt, int nb, int ne,
    int* __restrict__ bbase, int* __restrict__ bcur) {
    __shared__ int sh[256];
    int t = threadIdx.x;
    int v = (t < nb) ? gcnt[t] : 0;
    sh[t] = v;
    __syncthreads();
    for (int o = 1; o < 256; o <<= 1) {
        int x = (t >= o) ? sh[t - o] : 0;
        __syncthreads();
        sh[t] += x;
        __syncthreads();
    }
    int excl = sh[t] - v;
    if (t < nb) { bbase[t] = excl; bcur[t] = excl; }
    if (t == nb) bbase[t] = ne;
    if (t == 0 && nb == 256) bbase[256] = ne;
}

__global__ __launch_bounds__(256) void bscatter_kernel(
    const int* __restrict__ edges, int ne,
    int* __restrict__ bcur, int* __restrict__ packed) {
    __shared__ int h[256];
    __shared__ int chunkb[256];
    __shared__ int lcur[256];
    __shared__ int f64;
    int t = threadIdx.x;
    bool is64 = detect_is64(edges, &f64, t);
    h[t] = 0;
    lcur[t] = 0;
    __syncthreads();
    int base_e = blockIdx.x * EPB;
    int ent[EPB / 256], eb[EPB / 256];
    #pragma unroll
    for (int u = 0; u < EPB / 256; ++u) {
        int i = base_e + u * 256 + t;
        if (i < ne) {
            int s, d;
            edge_sd(edges, i, ne, is64, s, d);
            ent[u] = s | ((d & 255) << 24);
            eb[u] = d >> 8;
            atomicAdd(&h[eb[u]], 1);
        } else eb[u] = -1;
    }
    __syncthreads();
    if (h[t]) chunkb[t] = atomicAdd(&bcur[t], h[t]);
    __syncthreads();
    #pragma unroll
    for (int u = 0; u < EPB / 256; ++u) {
        if (eb[u] >= 0) {
            int lp = atomicAdd(&lcur[eb[u]], 1);
            packed[chunkb[eb[u]] + lp] = ent[u];
        }
    }
}

__global__ __launch_bounds__(256) void bbuild_kernel(
    const int* __restrict__ packed, const int* __restrict__ bbase,
    int* __restrict__ rowptr, int* __restrict__ csr_src, int n) {
    __shared__ int h[256];
    __shared__ int cur[256];
    int t = threadIdx.x;
    int bb = blockIdx.x;
    int base = bbase[bb], cnt = bbase[bb + 1] - base;
    h[t] = 0;
    __syncthreads();
    for (int i = t; i < cnt; i += 256)
        atomicAdd(&h[(unsigned)packed[base + i] >> 24], 1);
    __syncthreads();
    int v = h[t];
    for (int o = 1; o < 256; o <<= 1) {
        int x = (t >= o) ? h[t - o] : 0;
        __syncthreads();
        h[t] += x;
        __syncthreads();
    }
    int excl = h[t] - v;
    int node = bb * 256 + t;
    if (node <= n) rowptr[node] = base + excl;
    cur[t] = excl;
    __syncthreads();
    for (int i = t; i < cnt; i += 256) {
        int e = packed[base + i];
        int lp = atomicAdd(&cur[(unsigned)e >> 24], 1);
        csr_src[base + lp] = e & 0xffffff;
    }
}

// ---------------- merged prep: x->bf16 + 3 transposed weight preps ---------
__global__ void prep_all_kernel(
    const float* __restrict__ x, ushort_t* __restrict__ xb, int nxb,
    const float* __restrict__ Wl0, const float* __restrict__ Wr0,
    ushort_t* __restrict__ WT0, int nb0,
    const float* __restrict__ Wl1, const float* __restrict__ Wr1,
    ushort_t* __restrict__ WT1c, int nb1,
    const float* __restrict__ Wl2, const float* __restrict__ Wr2,
    ushort_t* __restrict__ WT2c) {
    const int D0 = 128, D1 = 512, D2 = 256, D3 = 128;
    int b = blockIdx.x;
    if (b < nxb) {
        int i = b * 256 + threadIdx.x;
        xb[i] = f2bf(x[i]);
        return;
    }
    b -= nxb;
    if (b < nb0) {
        int idx = b * 256 + threadIdx.x;
        int K2 = 2 * D0;
        int nn = idx / K2, k = idx - nn * K2;
        float v = (k < D0) ? Wl0[(size_t)k * D1 + nn] : Wr0[(size_t)(k - D0) * D1 + nn];
        WT0[idx] = f2bf(v);
        return;
    }
    b -= nb0;
    if (b < nb1) {
        int idx = b * 256 + threadIdx.x;
        int nn = idx / D1, k = idx - nn * D1;
        float v = (nn < D2) ? Wl1[(size_t)k * D2 + nn] : Wr1[(size_t)k * D2 + (nn - D2)];
        WT1c[idx] = f2bf(v);
        return;
    }
    b -= nb1;
    {
        int idx = b * 256 + threadIdx.x;
        int nn = idx / D2, k = idx - nn * D2;
        float v = (nn < D3) ? Wl2[(size_t)k * D3 + nn] : Wr2[(size_t)k * D3 + (nn - D3)];
        WT2c[idx] = f2bf(v);
    }
}

// ---------------- aggregation helpers --------------------------------------
template <int VEC> struct VecT;
template <> struct VecT<2> { using T = unsigned int; };
template <> struct VecT<4> { using T = uint2v; };
template <> struct VecT<8> { using T = uint4v; };

template <int VEC>
__device__ __forceinline__ void vunpack(typename VecT<VEC>::T v, unsigned int* w) {
    if constexpr (VEC == 2) { w[0] = v; }
    else if constexpr (VEC == 4) { w[0] = v.x; w[1] = v.y; }
    else { w[0] = v.x; w[1] = v.y; w[2] = v.z; w[3] = v.w; }
}

template <int VEC>
__device__ __forceinline__ void vaccum(typename VecT<VEC>::T v, float* acc) {
    unsigned int w[VEC / 2];
    vunpack<VEC>(v, w);
    #pragma unroll
    for (int i = 0; i < VEC / 2; ++i) {
        acc[2 * i + 0] += bflo(w[i]);
        acc[2 * i + 1] += bfhi(w[i]);
    }
}

// gather loop, x16 main unroll with cascade tail (order-preserving)
template <int VEC>
__device__ __forceinline__ void gather_sum(
    const ushort_t* __restrict__ base, const int* __restrict__ csr_src,
    int e0, int e1, int rstride, float* acc) {
    using VT = typename VecT<VEC>::T;
    int e = e0;
    for (; e + 16 <= e1; e += 16) {
        VT v[16];
        #pragma unroll
        for (int u = 0; u < 16; ++u)
            v[u] = *(const VT*)(base + (size_t)csr_src[e + u] * rstride);
        #pragma unroll
        for (int u = 0; u < 16; ++u) vaccum<VEC>(v[u], acc);
    }
    if (e + 8 <= e1) {
        VT v[8];
        #pragma unroll
        for (int u = 0; u < 8; ++u)
            v[u] = *(const VT*)(base + (size_t)csr_src[e + u] * rstride);
        #pragma unroll
        for (int u = 0; u < 8; ++u) vaccum<VEC>(v[u], acc);
        e += 8;
    }
    if (e + 4 <= e1) {
        VT v[4];
        #pragma unroll
        for (int u = 0; u < 4; ++u)
            v[u] = *(const VT*)(base + (size_t)csr_src[e + u] * rstride);
        #pragma unroll
        for (int u = 0; u < 4; ++u) vaccum<VEC>(v[u], acc);
        e += 4;
    }
    if (e + 2 <= e1) {
        VT v0 = *(const VT*)(base + (size_t)csr_src[e] * rstride);
        VT v1 = *(const VT*)(base + (size_t)csr_src[e + 1] * rstride);
        vaccum<VEC>(v0, acc); vaccum<VEC>(v1, acc);
        e += 2;
    }
    if (e < e1)
        vaccum<VEC>(*(const VT*)(base + (size_t)csr_src[e] * rstride), acc);
}

// ---------------- plain aggregation (layer 0): bf16 mean -------------------
// grid-stride at exactly-resident block count
template <int VEC>
__global__ __launch_bounds__(256) void aggregate_wave_kernel(
    const ushort_t* __restrict__ h, ushort_t* __restrict__ mean,
    const int* __restrict__ rowptr, const int* __restrict__ csr_src, int nnodes) {
    const int din = VEC * 64;
    const int wave = threadIdx.x >> 6;
    const int lane = threadIdx.x & 63;
    const int wstride = gridDim.x * 4;
    using VT = typename VecT<VEC>::T;
    for (int wid = blockIdx.x * 4 + wave; wid < nnodes; wid += wstride) {
        int e0 = rowptr[wid], e1 = rowptr[wid + 1];
        float acc[VEC];
        #pragma unroll
        for (int i = 0; i < VEC; ++i) acc[i] = 0.f;
        gather_sum<VEC>(h + (size_t)lane * VEC, csr_src, e0, e1, din, acc);

        int deg = e1 - e0;
        float scale = 1.0f / (float)(deg > 1 ? deg : 1);
        unsigned int o[VEC / 2];
        #pragma unroll
        for (int i = 0; i < VEC / 2; ++i)
            o[i] = (unsigned int)f2bf(acc[2 * i] * scale) |
                   ((unsigned int)f2bf(acc[2 * i + 1] * scale) << 16);
        VT ov;
        if constexpr (VEC == 2) { ov = o[0]; }
        else if constexpr (VEC == 4) { ov.x = o[0]; ov.y = o[1]; }
        else { ov.x = o[0]; ov.y = o[1]; ov.z = o[2]; ov.w = o[3]; }
        *(VT*)(mean + (size_t)wid * din + (size_t)lane * VEC) = ov;
    }
}

// ---------------- fused aggregate + add + BN-stats, bf16 out (L1/L2) -------
// Each col is owned by exactly one lane -> per-lane f32 sum/sumsq registers
// across the grid-stride loop; LDS-reduce across the 4 waves; 2*D atomics
// per block at the end (same order as the deleted colstats kernel).
template <int VEC>  // VEC = D/64
__global__ __launch_bounds__(256) void aggregate_add_kernel(
    const ushort_t* __restrict__ PR, const float* __restrict__ bias,
    ushort_t* __restrict__ pre,
    const int* __restrict__ rowptr, const int* __restrict__ csr_src, int nnodes,
    float* __restrict__ gsum, float* __restrict__ gsq) {
    const int D = VEC * 64;
    const int stride = 2 * D;
    __shared__ float s_red[2][4][VEC * 64];
    const int wave = threadIdx.x >> 6;
    const int lane = threadIdx.x & 63;
    const int wstride = gridDim.x * 4;
    using VT = typename VecT<VEC>::T;

    float ssum[VEC], ssq[VEC];
    #pragma unroll
    for (int i = 0; i < VEC; ++i) { ssum[i] = 0.f; ssq[i] = 0.f; }

    for (int wid = blockIdx.x * 4 + wave; wid < nnodes; wid += wstride) {
        int e0 = rowptr[wid], e1 = rowptr[wid + 1];
        float acc[VEC];
        #pragma unroll
        for (int i = 0; i < VEC; ++i) acc[i] = 0.f;
        gather_sum<VEC>(PR + (size_t)lane * VEC, csr_src, e0, e1, stride, acc);

        int deg = e1 - e0;
        float scale = 1.0f / (float)(deg > 1 ? deg : 1);

        VT rv = *(const VT*)(PR + (size_t)wid * stride + D + (size_t)lane * VEC);
        unsigned int rw[VEC / 2];
        vunpack<VEC>(rv, rw);
        float o[VEC];
        #pragma unroll
        for (int i = 0; i < VEC / 2; ++i) {
            o[2 * i + 0] = bflo(rw[i]);
            o[2 * i + 1] = bfhi(rw[i]);
        }
        #pragma unroll
        for (int i = 0; i < VEC; ++i) {
            o[i] += acc[i] * scale + bias[lane * VEC + i];
            ssum[i] += o[i];
            ssq[i] += o[i] * o[i];
        }

        unsigned int ow[VEC / 2];
        #pragma unroll
        for (int i = 0; i < VEC / 2; ++i)
            ow[i] = (unsigned int)f2bf(o[2 * i]) | ((unsigned int)f2bf(o[2 * i + 1]) << 16);
        VT ov;
        if constexpr (VEC == 2) { ov = ow[0]; }
        else if constexpr (VEC == 4) { ov.x = ow[0]; ov.y = ow[1]; }
        else { ov.x = ow[0]; ov.y = ow[1]; ov.z = ow[2]; ov.w = ow[3]; }
        *(VT*)(pre + (size_t)wid * D + (size_t)lane * VEC) = ov;
    }

    // block-level stats reduce (all threads reach here; no barrier in loop)
    #pragma unroll
    for (int i = 0; i < VEC; ++i) {
        s_red[0][wave][lane * VEC + i] = ssum[i];
        s_red[1][wave][lane * VEC + i] = ssq[i];
    }
    __syncthreads();
    int t = threadIdx.x;
    if (t < D) {
        float a = s_red[0][0][t] + s_red[0][1][t] + s_red[0][2][t] + s_red[0][3][t];
        float q = s_red[1][0][t] + s_red[1][1][t] + s_red[1][2][t] + s_red[1][3][t];
        atomicAdd(&gsum[t], a);
        atomicAdd(&gsq[t], q);
    }
}

// ---------------- MFMA GEMM, 128x128 tile, 256 thr, BK=32, 3-buf -----------
// Triple-buffered: stages kt+2 while computing kt; vmcnt(8) steady state
// (two K-steps of loads in flight), vmcnt(4)/vmcnt(0) drain ladder.
// 48 KB LDS -> 3 blocks/CU. launch_bounds(256,4). m204 bijective XCD-chunk
// swizzle. setprio around MFMA.
// DUAL: C = [A1|A2] @ BT^T ; BIAS adds bias[col]; STATS: fused BN col-stats.
// BNA: per-channel scale/shift+ReLU+bf16-round on A fragments after LDS
// read; fragment at LDS pos (quad^sw3) holds GLOBAL k-chunk quad (the
// staging swizzle is an involution) -> channel base k0 = kt*32 + quad*8.
template <bool DUAL, bool BIAS, bool STATS, bool BNA>
__global__ __launch_bounds__(256, 4) void gemm_glds_kernel(
    const ushort_t* __restrict__ A1, const ushort_t* __restrict__ A2,
    const ushort_t* __restrict__ BT, const float* __restrict__ bias,
    ushort_t* __restrict__ Cb, int N, int K1, int Ktot, int Wtot, int nxShift,
    float* __restrict__ gsum, float* __restrict__ gsq,
    const float* __restrict__ bsum, const float* __restrict__ bsq,
    const float* __restrict__ bng, const float* __restrict__ bnb) {
    __shared__ ushort_t As[3 * 128 * 32];  // 3 x 8 KB
    __shared__ ushort_t Bs[3 * 128 * 32];  // 3 x 8 KB
    __shared__ float bnsc[BNA ? 512 : 1];
    __shared__ float bnsh[BNA ? 512 : 1];

    const int tid = threadIdx.x;
    const int wave = tid >> 6;
    const int lane = tid & 63;
    const int quad = lane >> 4;
    const int l15 = lane & 15;
    const int sw3 = l15 & 3;

    // bijective XCD-chunk swizzle (m204): dispatch order o -> logical wgid
    const int nwg = gridDim.x;
    const int q = nwg >> 3, rr = nwg & 7;
    const int o = blockIdx.x;
    const int xcd = o & 7, sub = o >> 3;
    const int wgid = (xcd < rr ? xcd * (q + 1) : rr * (q + 1) + (xcd - rr) * q) + sub;
    const int bx = wgid & ((1 << nxShift) - 1);
    const int by = wgid >> nxShift;

    const int rowBase = by * 128;
    const int colBase = bx * 128;
    const int wm = (wave >> 1) * 64;   // 0/64
    const int wn = (wave & 1) * 64;    // 0/64

    if constexpr (BNA) {
        // build per-channel scale/shift table: v' = v*sc + sh, then ReLU
        for (int t = tid; t < K1; t += 256) {
            float m = bsum[t] / (float)N;
            float inv = rsqrtf(bsq[t] / (float)N - m * m + EPS_BN);
            float sc = bng[t] * inv;
            bnsc[t] = sc;
            bnsh[t] = bnb[t] - m * sc;
        }
        __syncthreads();
    }

    float4v acc[4][4];
    #pragma unroll
    for (int i = 0; i < 4; ++i)
        #pragma unroll
        for (int j = 0; j < 4; ++j)
            acc[i][j] = (float4v){0.f, 0.f, 0.f, 0.f};

    const int nkt = Ktot / 32;
    const int khalf = K1 / 32;

    // stage one BK=32 tile: A 512 x 16B chunks (2/thread), B same
    auto stage = [&](int buf, int kt) {
        const ushort_t* Asrc = A1;
        int kg = kt * 32;
        if (DUAL && kt >= khalf) { Asrc = A2; kg = (kt - khalf) * 32; }
        const int kb = kt * 32;
        #pragma unroll
        for (int u = 0; u < 2; ++u) {
            int c = u * 256 + tid;
            int r = c >> 2, cc = c & 3;
            int off = (cc ^ (r & 3)) * 8;
            int grow = rowBase + r;
            if (grow >= N) grow = N - 1;
            async_copy16(&As[buf * 4096 + c * 8], Asrc + (size_t)grow * K1 + kg + off);
        }
        #pragma unroll
        for (int u = 0; u < 2; ++u) {
            int c = u * 256 + tid;
            int r = c >> 2, cc = c & 3;
            int off = (cc ^ (r & 3)) * 8;
            async_copy16(&Bs[buf * 4096 + c * 8], BT + (size_t)(colBase + r) * Ktot + kb + off);
        }
    };

    stage(0, 0);
    if (nkt > 1) stage(1, 1);
    int cur = 0;
    for (int kt = 0; kt < nkt; ++kt) {
        if (kt + 2 < nkt) {
            int nb = cur + 2; if (nb >= 3) nb -= 3;
            stage(nb, kt + 2);
            // kt's 4 loads retired; kt+1's 4 + kt+2's 4 stay in flight
            asm volatile("s_waitcnt vmcnt(8)\n\ts_barrier" ::: "memory");
        } else if (kt + 1 < nkt) {
            asm volatile("s_waitcnt vmcnt(4)\n\ts_barrier" ::: "memory");
        } else {
            asm volatile("s_waitcnt vmcnt(0)\n\ts_barrier" ::: "memory");
        }

        short8 af[4], bf4[4];
        #pragma unroll
        for (int i = 0; i < 4; ++i)
            af[i] = *(const short8*)&As[cur * 4096 + (wm + i * 16 + l15) * 32 + (quad ^ sw3) * 8];
        #pragma unroll
        for (int j = 0; j < 4; ++j)
            bf4[j] = *(const short8*)&Bs[cur * 4096 + (wn + j * 16 + l15) * 32 + (quad ^ sw3) * 8];

        if constexpr (BNA) {
            // fragment holds GLOBAL k = kt*32 + quad*8 + [0,8)  (de-swizzled)
            int k0 = kt * 32 + quad * 8;
            #pragma unroll
            for (int e = 0; e < 8; ++e) {
                float sc = bnsc[k0 + e];
                float sh = bnsh[k0 + e];
                #pragma unroll
                for (int i = 0; i < 4; ++i) {
                    unsigned int u = ((unsigned int)(unsigned short)af[i][e]) << 16;
                    union { unsigned int w; float f; } cv; cv.w = u;
                    float v = cv.f * sc + sh;
                    v = v > 0.f ? v : 0.f;
                    af[i][e] = (short)f2bf(v);
                }
            }
        }

        __builtin_amdgcn_s_setprio(1);
        #pragma unroll
        for (int i = 0; i < 4; ++i)
            #pragma unroll
            for (int j = 0; j < 4; ++j)
                acc[i][j] = __builtin_amdgcn_mfma_f32_16x16x32_bf16(bf4[j], af[i], acc[i][j], 0, 0, 0);
        __builtin_amdgcn_s_setprio(0);
        // all waves done reading buf cur before a later stage() overwrites it
        asm volatile("s_barrier" ::: "memory");
        cur = (cur == 2) ? 0 : cur + 1;
    }

    float cs[4][4], cq[4][4];
    if constexpr (STATS) {
        #pragma unroll
        for (int j = 0; j < 4; ++j)
            #pragma unroll
            for (int r = 0; r < 4; ++r) { cs[j][r] = 0.f; cq[j][r] = 0.f; }
    }

    // epilogue: per-wave 4KB LDS restage -> full-line bf16 stores
    ushort_t* lws = &As[wave * 2048];  // 4 waves x 2048 shorts = 16 KB
    #pragma unroll
    for (int p = 0; p < 2; ++p) {
        #pragma unroll
        for (int jj = 0; jj < 2; ++jj) {
            int j = 2 * p + jj;
            float4 bv = make_float4(0.f, 0.f, 0.f, 0.f);
            if (BIAS) bv = *(const float4*)(bias + colBase + wn + j * 16 + quad * 4);
            #pragma unroll
            for (int i = 0; i < 4; ++i) {
                float v0 = acc[i][j][0] + bv.x;
                float v1 = acc[i][j][1] + bv.y;
                float v2 = acc[i][j][2] + bv.z;
                float v3 = acc[i][j][3] + bv.w;
                if constexpr (STATS) {
                    if (rowBase + wm + i * 16 + l15 < N) {
                        cs[j][0] += v0; cq[j][0] += v0 * v0;
                        cs[j][1] += v1; cq[j][1] += v1 * v1;
                        cs[j][2] += v2; cq[j][2] += v2 * v2;
                        cs[j][3] += v3; cq[j][3] += v3 * v3;
                    }
                }
                uint2 pk;
                pk.x = (unsigned int)f2bf(v0) | ((unsigned int)f2bf(v1) << 16);
                pk.y = (unsigned int)f2bf(v2) | ((unsigned int)f2bf(v3) << 16);
                *(uint2*)&lws[(i * 16 + l15) * 32 + jj * 16 + quad * 4] = pk;
            }
        }
        __syncthreads();
        #pragma unroll
        for (int it = 0; it < 4; ++it) {
            int c = it * 64 + lane;
            int row = c >> 2, coff = (c & 3) * 8;
            int grow = rowBase + wm + row;
            if (grow < N) {
                uint4 v = *(const uint4*)&lws[row * 32 + coff];
                *(uint4*)(Cb + (size_t)grow * Wtot + colBase + wn + p * 32 + coff) = v;
            }
        }
        __syncthreads();
    }

    if constexpr (STATS) {
        // reduce over l15 (16 lanes share same col, different rows)
        #pragma unroll
        for (int j = 0; j < 4; ++j)
            #pragma unroll
            for (int r = 0; r < 4; ++r) {
                #pragma unroll
                for (int m = 1; m < 16; m <<= 1) {
                    cs[j][r] += __shfl_xor(cs[j][r], m);
                    cq[j][r] += __shfl_xor(cq[j][r], m);
                }
            }
        if (l15 == 0) {
            #pragma unroll
            for (int j = 0; j < 4; ++j)
                #pragma unroll
                for (int r = 0; r < 4; ++r) {
                    int col = colBase + wn + j * 16 + quad * 4 + r;
                    atomicAdd(&gsum[col], cs[j][r]);
                    atomicAdd(&gsq[col], cq[j][r]);
                }
        }
    }
}

// ---------------- BN apply (bf16 in, f32 out: final layer) -----------------
__global__ void bn_relu_b2f_kernel(const ushort_t* __restrict__ h, float* __restrict__ hf,
                                   int N, int D,
                                   const float* __restrict__ sum, const float* __restrict__ sumsq,
                                   const float* __restrict__ g, const float* __restrict__ b) {
    size_t idx = (size_t)blockIdx.x * blockDim.x + threadIdx.x;
    size_t tot = (size_t)N * D / 2;
    if (idx >= tot) return;
    int cp = (int)(idx & (size_t)(D / 2 - 1));
    int c0 = cp * 2, c1 = c0 + 1;
    float m0 = sum[c0] / (float)N, m1 = sum[c1] / (float)N;
    float i0 = rsqrtf(sumsq[c0] / (float)N - m0 * m0 + EPS_BN);
    float i1 = rsqrtf(sumsq[c1] / (float)N - m1 * m1 + EPS_BN);
    unsigned int w = ((const unsigned int*)h)[idx];
    float v0 = g[c0] * (bflo(w) - m0) * i0 + b[c0];
    float v1 = g[c1] * (bfhi(w) - m1) * i1 + b[c1];
    float2v o;
    o.x = v0 > 0.f ? v0 : 0.f;
    o.y = v1 > 0.f ? v1 : 0.f;
    *(float2v*)(hf + idx * 2) = o;
}

// ---------------------------------------------------------------------------
extern "C" void kernel_launch(void* const* d_in, const int* in_sizes, int n_in,
                              void* d_out, int out_size, void* d_ws, size_t ws_size,
                              hipStream_t stream) {
    const float* x     = (const float*)d_in[0];
    const int*   edges = (const int*)d_in[1];
    const float* Wl0 = (const float*)d_in[2];
    const float* bl0 = (const float*)d_in[3];
    const float* Wr0 = (const float*)d_in[4];
    const float* g0  = (const float*)d_in[5];
    const float* b0  = (const float*)d_in[6];
    const float* Wl1 = (const float*)d_in[7];
    const float* bl1 = (const float*)d_in[8];
    const float* Wr1 = (const float*)d_in[9];
    const float* g1  = (const float*)d_in[10];
    const float* b1  = (const float*)d_in[11];
    const float* Wl2 = (const float*)d_in[12];
    const float* bl2 = (const float*)d_in[13];
    const float* Wr2 = (const float*)d_in[14];
    const float* g2  = (const float*)d_in[15];
    const float* b2  = (const float*)d_in[16];

    const int D0 = 128, D1 = 512, D2 = 256, D3 = 128;
    const int n  = in_sizes[0] / D0;   // 50000
    const int ne = in_sizes[1] / 2;    // 800000
    const int NB = (n + 255) >> 8;     // 196 buckets

    // ---- workspace layout (zeroed block first -> one memset) ----
    char* base = (char*)d_ws;
    size_t off = 0;
    auto alloc = [&](size_t bytes) -> char* {
        char* p = base + off;
        off = (off + bytes + 255) & ~(size_t)255;
        return p;
    };
    int*      gcnt    = (int*)alloc(256 * 4);
    float*    stats   = (float*)alloc(6 * 512 * 4);
    size_t    zero_span = off;
    int*      bbase   = (int*)alloc(257 * 4);
    int*      bcur    = (int*)alloc(256 * 4);
    int*      packed  = (int*)alloc((size_t)ne * 4);
    int*      rowptr  = (int*)alloc((size_t)(n + 1) * 4);
    int*      csr_src = (int*)alloc((size_t)ne * 4);
    ushort_t* xb      = (ushort_t*)alloc((size_t)n * D0 * 2);
    ushort_t* mb      = (ushort_t*)alloc((size_t)n * 512 * 2);   // mean(L0) / PR(L1,L2)
    ushort_t* hpre    = (ushort_t*)alloc((size_t)n * 512 * 2);   // bf16 pre-BN
    ushort_t* WT0     = (ushort_t*)alloc((size_t)D1 * 2 * D0 * 2);
    ushort_t* WT1c    = (ushort_t*)alloc((size_t)(2 * D2) * D1 * 2);
    ushort_t* WT2c    = (ushort_t*)alloc((size_t)(2 * D3) * D2 * 2);
    float*    out     = (float*)d_out;
    (void)ws_size; (void)n_in; (void)out_size;

    hipMemsetAsync(base, 0, zero_span, stream);

    // ---- bucket-sort CSR build (edge format detected in-block) ----
    int ablk = (ne + EPB - 1) / EPB;
    bhist_kernel<<<ablk, 256, 0, stream>>>(edges, ne, gcnt);
    bscan_kernel<<<1, 256, 0, stream>>>(gcnt, NB, ne, bbase, bcur);
    bscatter_kernel<<<ablk, 256, 0, stream>>>(edges, ne, bcur, packed);
    bbuild_kernel<<<NB, 256, 0, stream>>>(packed, bbase, rowptr, csr_src, n);

    // ---- merged prep (x->bf16 + all weight transposes) ----
    const int nxb = (n * D0) / 256;               // 25000
    const int nb0 = (D1 * 2 * D0) / 256;          // 512
    const int nb1 = (2 * D2 * D1) / 256;          // 1024
    const int nb2 = (2 * D3 * D2) / 256;          // 256
    prep_all_kernel<<<nxb + nb0 + nb1 + nb2, 256, 0, stream>>>(
        x, xb, nxb, Wl0, Wr0, WT0, nb0, Wl1, Wr1, WT1c, nb1, Wl2, Wr2, WT2c);

    const int aggGrid = 2048;                // exactly-resident: 8 blocks/CU
    const int rowBlocks = (n + 127) / 128;   // 128-row GEMM tiles (391)
    float* st0 = stats + 0 * 1024;
    float* st1 = stats + 1 * 1024;
    float* st2 = stats + 2 * 1024;

    // ---- layer 0: 128 -> 512 (aggregate-first: din < dout) ----
    aggregate_wave_kernel<2><<<aggGrid, 256, 0, stream>>>(xb, mb, rowptr, csr_src, n);
    gemm_glds_kernel<true, true, true, false><<<4 * rowBlocks, 256, 0, stream>>>(
        mb, xb, WT0, bl0, hpre, n, D0, 2 * D0, D1, 2, st0, st0 + 512,
        nullptr, nullptr, nullptr, nullptr);
    // (BN-apply for L0 fused into L1 GEMM's A path)

    // ---- layer 1: 512 -> 256 (project-first, fused [P|R], BN-A fused) ----
    gemm_glds_kernel<false, false, false, true><<<4 * rowBlocks, 256, 0, stream>>>(
        hpre, nullptr, WT1c, nullptr, mb, n, D1, D1, 2 * D2, 2, nullptr, nullptr,
        st0, st0 + 512, g0, b0);                                  // PR1 = bn(hpre) @ [Wl1|Wr1]
    aggregate_add_kernel<4><<<aggGrid, 256, 0, stream>>>(
        mb, bl1, hpre, rowptr, csr_src, n, st1, st1 + 512);       // pre = mean(P)+R+bl1 (+stats)

    // ---- layer 2: 256 -> 128 (project-first, fused [P|R], BN-A fused) ----
    gemm_glds_kernel<false, false, false, true><<<2 * rowBlocks, 256, 0, stream>>>(
        hpre, nullptr, WT2c, nullptr, mb, n, D2, D2, 2 * D3, 1, nullptr, nullptr,
        st1, st1 + 512, g1, b1);                                  // PR2 = bn(hpre) @ [Wl2|Wr2]
    aggregate_add_kernel<2><<<aggGrid, 256, 0, stream>>>(
        mb, bl2, hpre, rowptr, csr_src, n, st2, st2 + 512);       // pre = mean(P)+R+bl2 (+stats)
    bn_relu_b2f_kernel<<<((size_t)n * D3 / 2 + 255) / 256, 256, 0, stream>>>(
        hpre, out, n, D3, st2, st2 + 512, g2, b2);
}